// Round 1
// baseline (24.087 us; speedup 1.0000x reference)
//
#include <hip/hip_runtime.h>

// Problem constants (from reference setup_inputs)
#define NB 8
#define NG 512
#define NT 1024
#define NK 5
#define NC 3
#define TT 8   // targets per block
#define TW 2   // targets per wave (TT / 4 waves)

__global__ __launch_bounds__(256, 4)
void finallayer_kernel(const float* __restrict__ x_grid,
                       const float* __restrict__ h_grid,
                       const float* __restrict__ target_x,
                       const float* __restrict__ sigma,
                       const float* __restrict__ g_w,
                       const float* __restrict__ g_b,
                       float* __restrict__ out) {
    __shared__ float x_s[NG * NC];        // 6 KB
    __shared__ float hw_s[NG * NK * NC];  // 30 KB

    const int tid   = threadIdx.x;
    const int b     = blockIdx.x / (NT / TT);
    const int ttile = blockIdx.x % (NT / TT);

    // g_w into registers (5 scalar-ish loads)
    float gw[NK];
    #pragma unroll
    for (int k = 0; k < NK; ++k) gw[k] = g_w[k];

    // Stage x_grid[b] into LDS
    const float* xg = x_grid + b * NG * NC;
    for (int i = tid; i < NG * NC; i += 256) x_s[i] = xg[i];

    // Stage hw = h_grid[b] * g_w[k] into LDS (fold the output projection)
    const float* hg = h_grid + b * NG * NK * NC;
    for (int i = tid; i < NG * NK * NC; i += 256) {
        int r = i % (NK * NC);           // = k*NC + c
        hw_s[i] = hg[i] * gw[r / NC];
    }

    // coef[k][c] = -0.5 / scale^2, scale = exp(sigma)+eps  (15 tiny transcendentals/thread)
    float coef[NK][NC];
    #pragma unroll
    for (int k = 0; k < NK; ++k) {
        #pragma unroll
        for (int c = 0; c < NC; ++c) {
            float s = __expf(sigma[k * NC + c]) + 1e-6f;
            coef[k][c] = -0.5f / (s * s);
        }
    }

    __syncthreads();

    const int wave = tid >> 6;
    const int lane = tid & 63;
    const int t0   = ttile * TT + wave * TW;

    // Broadcast target coordinates for this wave's targets
    float tx[TW][NC];
    #pragma unroll
    for (int t = 0; t < TW; ++t) {
        #pragma unroll
        for (int c = 0; c < NC; ++c)
            tx[t][c] = target_x[(b * NT + t0 + t) * NC + c];
    }

    float acc[TW][NC] = {};

    // lane l covers g = l + 64*i ; x/hw held in registers, reused across TW targets
    #pragma unroll 1
    for (int i = 0; i < NG / 64; ++i) {
        const int g = lane + i * 64;

        float xv[NC];
        #pragma unroll
        for (int c = 0; c < NC; ++c) xv[c] = x_s[g * NC + c];

        float hw[NK][NC];
        #pragma unroll
        for (int k = 0; k < NK; ++k) {
            #pragma unroll
            for (int c = 0; c < NC; ++c)
                hw[k][c] = hw_s[(g * NK + k) * NC + c];
        }

        #pragma unroll
        for (int t = 0; t < TW; ++t) {
            float d2[NC];
            #pragma unroll
            for (int c = 0; c < NC; ++c) {
                float d = xv[c] - tx[t][c];
                d2[c] = d * d;
            }
            #pragma unroll
            for (int k = 0; k < NK; ++k) {
                #pragma unroll
                for (int c = 0; c < NC; ++c)
                    acc[t][c] += hw[k][c] * __expf(d2[c] * coef[k][c]);
            }
        }
    }

    // Intra-wave reduction over the 64 g-lanes (no cross-wave reduce needed)
    #pragma unroll
    for (int t = 0; t < TW; ++t) {
        #pragma unroll
        for (int c = 0; c < NC; ++c) {
            float v = acc[t][c];
            #pragma unroll
            for (int off = 32; off > 0; off >>= 1)
                v += __shfl_down(v, off);
            acc[t][c] = v;
        }
    }

    if (lane == 0) {
        const float gb = g_b[0];
        #pragma unroll
        for (int t = 0; t < TW; ++t) {
            #pragma unroll
            for (int c = 0; c < NC; ++c)
                out[(b * NT + t0 + t) * NC + c] = acc[t][c] + gb;
        }
    }
}

extern "C" void kernel_launch(void* const* d_in, const int* in_sizes, int n_in,
                              void* d_out, int out_size, void* d_ws, size_t ws_size,
                              hipStream_t stream) {
    const float* x_grid   = (const float*)d_in[0];
    const float* h_grid   = (const float*)d_in[1];
    const float* target_x = (const float*)d_in[2];
    const float* sigma    = (const float*)d_in[3];
    const float* g_w      = (const float*)d_in[4];
    const float* g_b      = (const float*)d_in[5];
    float* out = (float*)d_out;

    const int grid = NB * (NT / TT);  // 1024 blocks
    finallayer_kernel<<<grid, 256, 0, stream>>>(x_grid, h_grid, target_x,
                                                sigma, g_w, g_b, out);
}

// Round 2
// 15.747 us; speedup vs baseline: 1.5296x; 1.5296x over previous
//
#include <hip/hip_runtime.h>

// Problem constants (from reference setup_inputs)
#define NB 8
#define NG 512
#define NT 1024
#define NK 5
#define NC 3
#define TT 8   // targets per block (main kernel)
#define TW 2   // targets per wave (TT / 4 waves)

// 0.5 * log2(e)
#define HALF_LOG2E 0.72134752044448170f

#if defined(__has_builtin)
#if __has_builtin(__builtin_amdgcn_exp2f)
#define EXP2F(x) __builtin_amdgcn_exp2f(x)
#else
#define EXP2F(x) exp2f(x)
#endif
#else
#define EXP2F(x) exp2f(x)
#endif

// Workspace layout (floats): xb[b][c][g] (pre-scaled x), then hsum[b][c][g].
// Total 2 * NB*NC*NG * 4B = 96 KB.

__global__ __launch_bounds__(256)
void pre_kernel(const float* __restrict__ x_grid,
                const float* __restrict__ h_grid,
                const float* __restrict__ sigma,
                const float* __restrict__ g_w,
                float* __restrict__ ws) {
    const int idx = blockIdx.x * blockDim.x + threadIdx.x;  // (b, g)
    if (idx >= NB * NG) return;
    const int b = idx / NG, g = idx % NG;

    float gw[NK];
    #pragma unroll
    for (int k = 0; k < NK; ++k) gw[k] = g_w[k];

    // beta[c] = sqrt(0.5*log2e) / scale[c], from the k=0 sigma row
    // (only used by main kernel's fast path, which requires k-uniform sigma)
    float beta[NC];
    #pragma unroll
    for (int c = 0; c < NC; ++c) {
        float s = __expf(sigma[c]) + 1e-6f;
        beta[c] = sqrtf(HALF_LOG2E) / s;
    }

    float* __restrict__ xb = ws;
    float* __restrict__ hs = ws + NB * NC * NG;

    #pragma unroll
    for (int c = 0; c < NC; ++c) {
        xb[(b * NC + c) * NG + g] = x_grid[(b * NG + g) * NC + c] * beta[c];
        float acc = 0.f;
        #pragma unroll
        for (int k = 0; k < NK; ++k)
            acc += gw[k] * h_grid[((b * NG + g) * NK + k) * NC + c];
        hs[(b * NC + c) * NG + g] = acc;
    }
}

__global__ __launch_bounds__(256)
void main_kernel(const float* __restrict__ x_grid,
                 const float* __restrict__ h_grid,
                 const float* __restrict__ target_x,
                 const float* __restrict__ sigma,
                 const float* __restrict__ g_w,
                 const float* __restrict__ g_b,
                 const float* __restrict__ ws,
                 float* __restrict__ out) {
    const int tid   = threadIdx.x;
    const int b     = blockIdx.x / (NT / TT);
    const int ttile = blockIdx.x % (NT / TT);
    const int wave  = tid >> 6;
    const int lane  = tid & 63;
    const int t0    = ttile * TT + wave * TW;

    // Runtime check: is sigma identical across k for each c? (exact compare;
    // uniform branch). True for the module's init; fast path is 5x less work.
    float sig0[NC];
    #pragma unroll
    for (int c = 0; c < NC; ++c) sig0[c] = sigma[c];
    bool kuni = true;
    #pragma unroll
    for (int k = 1; k < NK; ++k)
        #pragma unroll
        for (int c = 0; c < NC; ++c)
            kuni = kuni && (sigma[k * NC + c] == sig0[c]);

    float acc[TW][NC] = {};

    if (kuni) {
        // ---- fast path: k-sum folded into hsum; exp arg pre-scaled ----
        float tb[TW][NC];
        #pragma unroll
        for (int c = 0; c < NC; ++c) {
            float s = __expf(sig0[c]) + 1e-6f;
            float beta = sqrtf(HALF_LOG2E) / s;
            #pragma unroll
            for (int t = 0; t < TW; ++t)
                tb[t][c] = target_x[(b * NT + t0 + t) * NC + c] * beta;
        }
        const float* __restrict__ xb = ws + b * NC * NG;
        const float* __restrict__ hs = ws + NB * NC * NG + b * NC * NG;

        #pragma unroll
        for (int i = 0; i < NG / 64; ++i) {
            const int g = lane + i * 64;
            float xv[NC], hv[NC];
            #pragma unroll
            for (int c = 0; c < NC; ++c) {
                xv[c] = xb[c * NG + g];   // SoA: fully coalesced, L1-resident
                hv[c] = hs[c * NG + g];
            }
            #pragma unroll
            for (int t = 0; t < TW; ++t) {
                #pragma unroll
                for (int c = 0; c < NC; ++c) {
                    float a = xv[c] - tb[t][c];
                    acc[t][c] += hv[c] * EXP2F(-(a * a));  // neg is a free src modifier
                }
            }
        }
    } else {
        // ---- general fallback (not exercised by this bench's inputs) ----
        float gw[NK], coef[NK][NC], txr[TW][NC];
        #pragma unroll
        for (int k = 0; k < NK; ++k) gw[k] = g_w[k];
        #pragma unroll
        for (int k = 0; k < NK; ++k)
            #pragma unroll
            for (int c = 0; c < NC; ++c) {
                float s = __expf(sigma[k * NC + c]) + 1e-6f;
                coef[k][c] = -HALF_LOG2E / (s * s);
            }
        #pragma unroll
        for (int t = 0; t < TW; ++t)
            #pragma unroll
            for (int c = 0; c < NC; ++c)
                txr[t][c] = target_x[(b * NT + t0 + t) * NC + c];

        #pragma unroll 1
        for (int i = 0; i < NG / 64; ++i) {
            const int g = lane + i * 64;
            float xv[NC];
            #pragma unroll
            for (int c = 0; c < NC; ++c)
                xv[c] = x_grid[(b * NG + g) * NC + c];
            float hv[NK][NC];
            #pragma unroll
            for (int k = 0; k < NK; ++k)
                #pragma unroll
                for (int c = 0; c < NC; ++c)
                    hv[k][c] = gw[k] * h_grid[((b * NG + g) * NK + k) * NC + c];
            #pragma unroll
            for (int t = 0; t < TW; ++t) {
                float d2[NC];
                #pragma unroll
                for (int c = 0; c < NC; ++c) {
                    float d = xv[c] - txr[t][c];
                    d2[c] = d * d;
                }
                #pragma unroll
                for (int k = 0; k < NK; ++k)
                    #pragma unroll
                    for (int c = 0; c < NC; ++c)
                        acc[t][c] += hv[k][c] * EXP2F(d2[c] * coef[k][c]);
            }
        }
    }

    // Intra-wave reduction over the 64 g-lanes
    #pragma unroll
    for (int t = 0; t < TW; ++t)
        #pragma unroll
        for (int c = 0; c < NC; ++c) {
            float v = acc[t][c];
            #pragma unroll
            for (int off = 32; off > 0; off >>= 1)
                v += __shfl_down(v, off);
            acc[t][c] = v;
        }

    if (lane == 0) {
        const float gb = g_b[0];
        #pragma unroll
        for (int t = 0; t < TW; ++t)
            #pragma unroll
            for (int c = 0; c < NC; ++c)
                out[(b * NT + t0 + t) * NC + c] = acc[t][c] + gb;
    }
}

extern "C" void kernel_launch(void* const* d_in, const int* in_sizes, int n_in,
                              void* d_out, int out_size, void* d_ws, size_t ws_size,
                              hipStream_t stream) {
    const float* x_grid   = (const float*)d_in[0];
    const float* h_grid   = (const float*)d_in[1];
    const float* target_x = (const float*)d_in[2];
    const float* sigma    = (const float*)d_in[3];
    const float* g_w      = (const float*)d_in[4];
    const float* g_b      = (const float*)d_in[5];
    float* ws  = (float*)d_ws;
    float* out = (float*)d_out;

    pre_kernel<<<(NB * NG + 255) / 256, 256, 0, stream>>>(x_grid, h_grid, sigma, g_w, ws);

    const int grid = NB * (NT / TT);  // 1024 blocks
    main_kernel<<<grid, 256, 0, stream>>>(x_grid, h_grid, target_x,
                                          sigma, g_w, g_b, ws, out);
}

// Round 3
// 10.997 us; speedup vs baseline: 2.1904x; 1.4320x over previous
//
#include <hip/hip_runtime.h>

// Problem constants (from reference setup_inputs)
#define NB 8
#define NG 512
#define NT 1024
#define NK 5
#define NC 3
#define TT 8   // targets per block
#define TW 2   // targets per wave (TT / 4 waves)

// 0.5 * log2(e)
#define HALF_LOG2E 0.72134752044448170f

#if defined(__has_builtin)
#if __has_builtin(__builtin_amdgcn_exp2f)
#define EXP2F(x) __builtin_amdgcn_exp2f(x)
#else
#define EXP2F(x) exp2f(x)
#endif
#else
#define EXP2F(x) exp2f(x)
#endif

__global__ __launch_bounds__(256)
void fused_kernel(const float* __restrict__ x_grid,
                  const float* __restrict__ h_grid,
                  const float* __restrict__ target_x,
                  const float* __restrict__ sigma,
                  const float* __restrict__ g_w,
                  const float* __restrict__ g_b,
                  float* __restrict__ out) {
    // SoA tiles for this block's b: xb_s[c][g] = x*beta, hs_s[c][g] = sum_k gw[k]*h
    __shared__ float xb_s[NC][NG];   // 6 KB
    __shared__ float hs_s[NC][NG];   // 6 KB

    const int tid   = threadIdx.x;
    const int b     = blockIdx.x / (NT / TT);
    const int ttile = blockIdx.x % (NT / TT);
    const int wave  = tid >> 6;
    const int lane  = tid & 63;
    const int t0    = ttile * TT + wave * TW;

    // Runtime check: sigma identical across k for each c? (uniform branch;
    // true for this module's init -> 5x fewer exps). Fallback stays correct.
    float sig0[NC];
    #pragma unroll
    for (int c = 0; c < NC; ++c) sig0[c] = sigma[c];
    bool kuni = true;
    #pragma unroll
    for (int k = 1; k < NK; ++k)
        #pragma unroll
        for (int c = 0; c < NC; ++c)
            kuni = kuni && (sigma[k * NC + c] == sig0[c]);

    float acc[TW][NC] = {};

    if (kuni) {
        // ---- fast path ----
        float beta[NC];
        #pragma unroll
        for (int c = 0; c < NC; ++c) {
            float s = __expf(sig0[c]) + 1e-6f;
            beta[c] = sqrtf(HALF_LOG2E) / s;
        }
        float gw[NK];
        #pragma unroll
        for (int k = 0; k < NK; ++k) gw[k] = g_w[k];

        // Stage: thread tid owns g = 2*tid, 2*tid+1 -> 30 contiguous h floats
        {
            const float* __restrict__ hp = h_grid + (size_t)b * NG * NK * NC + tid * 2 * NK * NC;
            const float* __restrict__ xp = x_grid + (size_t)b * NG * NC + tid * 2 * NC;
            #pragma unroll
            for (int gg = 0; gg < 2; ++gg) {
                const int g = tid * 2 + gg;
                float hs[NC] = {};
                #pragma unroll
                for (int k = 0; k < NK; ++k)
                    #pragma unroll
                    for (int c = 0; c < NC; ++c)
                        hs[c] += gw[k] * hp[gg * NK * NC + k * NC + c];
                #pragma unroll
                for (int c = 0; c < NC; ++c) {
                    hs_s[c][g] = hs[c];
                    xb_s[c][g] = xp[gg * NC + c] * beta[c];
                }
            }
        }

        // Target coords (pre-scaled), per wave
        float tb[TW][NC];
        #pragma unroll
        for (int t = 0; t < TW; ++t)
            #pragma unroll
            for (int c = 0; c < NC; ++c)
                tb[t][c] = target_x[((size_t)b * NT + t0 + t) * NC + c] * beta[c];

        __syncthreads();

        // Main loop: lane covers g = lane + 64*i, stride-1 LDS (conflict-free)
        #pragma unroll
        for (int i = 0; i < NG / 64; ++i) {
            const int g = lane + i * 64;
            float xv[NC], hv[NC];
            #pragma unroll
            for (int c = 0; c < NC; ++c) {
                xv[c] = xb_s[c][g];
                hv[c] = hs_s[c][g];
            }
            #pragma unroll
            for (int t = 0; t < TW; ++t) {
                #pragma unroll
                for (int c = 0; c < NC; ++c) {
                    float a = xv[c] - tb[t][c];
                    acc[t][c] += hv[c] * EXP2F(-(a * a));  // neg = free src modifier
                }
            }
        }
    } else {
        // ---- general fallback (arbitrary sigma; reads global directly) ----
        float gw[NK], coef[NK][NC], txr[TW][NC];
        #pragma unroll
        for (int k = 0; k < NK; ++k) gw[k] = g_w[k];
        #pragma unroll
        for (int k = 0; k < NK; ++k)
            #pragma unroll
            for (int c = 0; c < NC; ++c) {
                float s = __expf(sigma[k * NC + c]) + 1e-6f;
                coef[k][c] = -HALF_LOG2E / (s * s);
            }
        #pragma unroll
        for (int t = 0; t < TW; ++t)
            #pragma unroll
            for (int c = 0; c < NC; ++c)
                txr[t][c] = target_x[((size_t)b * NT + t0 + t) * NC + c];

        #pragma unroll 1
        for (int i = 0; i < NG / 64; ++i) {
            const int g = lane + i * 64;
            float xv[NC];
            #pragma unroll
            for (int c = 0; c < NC; ++c)
                xv[c] = x_grid[((size_t)b * NG + g) * NC + c];
            float hv[NK][NC];
            #pragma unroll
            for (int k = 0; k < NK; ++k)
                #pragma unroll
                for (int c = 0; c < NC; ++c)
                    hv[k][c] = gw[k] * h_grid[(((size_t)b * NG + g) * NK + k) * NC + c];
            #pragma unroll
            for (int t = 0; t < TW; ++t) {
                float d2[NC];
                #pragma unroll
                for (int c = 0; c < NC; ++c) {
                    float d = xv[c] - txr[t][c];
                    d2[c] = d * d;
                }
                #pragma unroll
                for (int k = 0; k < NK; ++k)
                    #pragma unroll
                    for (int c = 0; c < NC; ++c)
                        acc[t][c] += hv[k][c] * EXP2F(d2[c] * coef[k][c]);
            }
        }
    }

    // Intra-wave reduction over the 64 g-lanes
    #pragma unroll
    for (int t = 0; t < TW; ++t)
        #pragma unroll
        for (int c = 0; c < NC; ++c) {
            float v = acc[t][c];
            #pragma unroll
            for (int off = 32; off > 0; off >>= 1)
                v += __shfl_down(v, off);
            acc[t][c] = v;
        }

    if (lane == 0) {
        const float gb = g_b[0];
        #pragma unroll
        for (int t = 0; t < TW; ++t)
            #pragma unroll
            for (int c = 0; c < NC; ++c)
                out[((size_t)b * NT + t0 + t) * NC + c] = acc[t][c] + gb;
    }
}

extern "C" void kernel_launch(void* const* d_in, const int* in_sizes, int n_in,
                              void* d_out, int out_size, void* d_ws, size_t ws_size,
                              hipStream_t stream) {
    const float* x_grid   = (const float*)d_in[0];
    const float* h_grid   = (const float*)d_in[1];
    const float* target_x = (const float*)d_in[2];
    const float* sigma    = (const float*)d_in[3];
    const float* g_w      = (const float*)d_in[4];
    const float* g_b      = (const float*)d_in[5];
    float* out = (float*)d_out;

    const int grid = NB * (NT / TT);  // 1024 blocks
    fused_kernel<<<grid, 256, 0, stream>>>(x_grid, h_grid, target_x,
                                           sigma, g_w, g_b, out);
}

// Round 4
// 10.506 us; speedup vs baseline: 2.2927x; 1.0467x over previous
//
#include <hip/hip_runtime.h>

// Problem constants (from reference setup_inputs)
#define NB 8
#define NG 512
#define NT 1024
#define NK 5
#define NC 3
#define TT 32  // targets per block
#define TW 8   // targets per wave (TT / 4 waves)

// 0.5 * log2(e)
#define HALF_LOG2E 0.72134752044448170f

#if defined(__has_builtin)
#if __has_builtin(__builtin_amdgcn_exp2f)
#define EXP2F(x) __builtin_amdgcn_exp2f(x)
#else
#define EXP2F(x) exp2f(x)
#endif
#else
#define EXP2F(x) exp2f(x)
#endif

// Wave64 sum via DPP (VALU pipe, not LDS pipe). Result valid in lane 63.
template <int CTRL>
__device__ __forceinline__ float dpp_add(float v) {
    int x = __builtin_amdgcn_update_dpp(0, __float_as_int(v), CTRL, 0xf, 0xf, true);
    return v + __int_as_float(x);
}
__device__ __forceinline__ float wave_sum_lane63(float v) {
    v = dpp_add<0x111>(v);  // row_shr:1
    v = dpp_add<0x112>(v);  // row_shr:2
    v = dpp_add<0x114>(v);  // row_shr:4
    v = dpp_add<0x118>(v);  // row_shr:8  -> lane 15 of each 16-row = row sum
    v = dpp_add<0x142>(v);  // row_bcast:15
    v = dpp_add<0x143>(v);  // row_bcast:31 -> lane 63 = wave sum
    return v;
}

__global__ __launch_bounds__(256)
void fused_kernel(const float* __restrict__ x_grid,
                  const float* __restrict__ h_grid,
                  const float* __restrict__ target_x,
                  const float* __restrict__ sigma,
                  const float* __restrict__ g_w,
                  const float* __restrict__ g_b,
                  float* __restrict__ out) {
    // float4-padded SoA tiles: .x/.y/.z = channels, .w = pad. 16 KB total.
    __shared__ float4 xb_s[NG];   // x * beta
    __shared__ float4 hs_s[NG];   // sum_k gw[k] * h

    const int tid   = threadIdx.x;
    const int b     = blockIdx.x / (NT / TT);
    const int ttile = blockIdx.x % (NT / TT);
    const int wave  = tid >> 6;
    const int lane  = tid & 63;
    const int t0    = ttile * TT + wave * TW;

    // Runtime check: sigma identical across k for each c? (uniform branch;
    // true for this module's init -> 5x fewer exps). Fallback stays correct.
    float sig0[NC];
    #pragma unroll
    for (int c = 0; c < NC; ++c) sig0[c] = sigma[c];
    bool kuni = true;
    #pragma unroll
    for (int k = 1; k < NK; ++k)
        #pragma unroll
        for (int c = 0; c < NC; ++c)
            kuni = kuni && (sigma[k * NC + c] == sig0[c]);

    if (kuni) {
        // ---- fast path ----
        float beta[NC];
        #pragma unroll
        for (int c = 0; c < NC; ++c) {
            float s = __expf(sig0[c]) + 1e-6f;
            beta[c] = sqrtf(HALF_LOG2E) / s;
        }
        float gw[NK];
        #pragma unroll
        for (int k = 0; k < NK; ++k) gw[k] = g_w[k];

        // Stage: thread tid owns g = 2*tid, 2*tid+1 -> 30 contiguous h floats
        {
            const float* __restrict__ hp = h_grid + (size_t)b * NG * NK * NC + tid * 2 * NK * NC;
            const float* __restrict__ xp = x_grid + (size_t)b * NG * NC + tid * 2 * NC;
            #pragma unroll
            for (int gg = 0; gg < 2; ++gg) {
                const int g = tid * 2 + gg;
                float hs[NC] = {};
                #pragma unroll
                for (int k = 0; k < NK; ++k)
                    #pragma unroll
                    for (int c = 0; c < NC; ++c)
                        hs[c] += gw[k] * hp[gg * NK * NC + k * NC + c];
                hs_s[g] = make_float4(hs[0], hs[1], hs[2], 0.f);
                xb_s[g] = make_float4(xp[gg * NC + 0] * beta[0],
                                      xp[gg * NC + 1] * beta[1],
                                      xp[gg * NC + 2] * beta[2], 0.f);
            }
        }

        // Target coords (pre-scaled), per wave
        float tb[TW][NC];
        #pragma unroll
        for (int t = 0; t < TW; ++t)
            #pragma unroll
            for (int c = 0; c < NC; ++c)
                tb[t][c] = target_x[((size_t)b * NT + t0 + t) * NC + c] * beta[c];

        __syncthreads();

        float acc[TW][NC] = {};

        // Main loop: lane covers g = lane + 64*i; 2x ds_read_b128 per iter
        #pragma unroll 2
        for (int i = 0; i < NG / 64; ++i) {
            const int g = lane + i * 64;
            const float4 xv = xb_s[g];
            const float4 hv = hs_s[g];
            #pragma unroll
            for (int t = 0; t < TW; ++t) {
                float a0 = xv.x - tb[t][0];
                float a1 = xv.y - tb[t][1];
                float a2 = xv.z - tb[t][2];
                acc[t][0] += hv.x * EXP2F(-(a0 * a0));
                acc[t][1] += hv.y * EXP2F(-(a1 * a1));
                acc[t][2] += hv.z * EXP2F(-(a2 * a2));
            }
        }

        // DPP wave reduction (VALU pipe); sums land in lane 63
        #pragma unroll
        for (int t = 0; t < TW; ++t)
            #pragma unroll
            for (int c = 0; c < NC; ++c)
                acc[t][c] = wave_sum_lane63(acc[t][c]);

        if (lane == 63) {
            const float gb = g_b[0];
            #pragma unroll
            for (int t = 0; t < TW; ++t)
                #pragma unroll
                for (int c = 0; c < NC; ++c)
                    out[((size_t)b * NT + t0 + t) * NC + c] = acc[t][c] + gb;
        }
    } else {
        // ---- general fallback (arbitrary sigma; reads global directly) ----
        float gw[NK], coef[NK][NC], txr[TW][NC];
        #pragma unroll
        for (int k = 0; k < NK; ++k) gw[k] = g_w[k];
        #pragma unroll
        for (int k = 0; k < NK; ++k)
            #pragma unroll
            for (int c = 0; c < NC; ++c) {
                float s = __expf(sigma[k * NC + c]) + 1e-6f;
                coef[k][c] = -HALF_LOG2E / (s * s);
            }
        #pragma unroll
        for (int t = 0; t < TW; ++t)
            #pragma unroll
            for (int c = 0; c < NC; ++c)
                txr[t][c] = target_x[((size_t)b * NT + t0 + t) * NC + c];

        float acc[TW][NC] = {};

        #pragma unroll 1
        for (int i = 0; i < NG / 64; ++i) {
            const int g = lane + i * 64;
            float xv[NC];
            #pragma unroll
            for (int c = 0; c < NC; ++c)
                xv[c] = x_grid[((size_t)b * NG + g) * NC + c];
            float hv[NK][NC];
            #pragma unroll
            for (int k = 0; k < NK; ++k)
                #pragma unroll
                for (int c = 0; c < NC; ++c)
                    hv[k][c] = gw[k] * h_grid[(((size_t)b * NG + g) * NK + k) * NC + c];
            #pragma unroll
            for (int t = 0; t < TW; ++t) {
                float d2[NC];
                #pragma unroll
                for (int c = 0; c < NC; ++c) {
                    float d = xv[c] - txr[t][c];
                    d2[c] = d * d;
                }
                #pragma unroll
                for (int k = 0; k < NK; ++k)
                    #pragma unroll
                    for (int c = 0; c < NC; ++c)
                        acc[t][c] += hv[k][c] * EXP2F(d2[c] * coef[k][c]);
            }
        }

        #pragma unroll
        for (int t = 0; t < TW; ++t)
            #pragma unroll
            for (int c = 0; c < NC; ++c)
                acc[t][c] = wave_sum_lane63(acc[t][c]);

        if (lane == 63) {
            const float gb = g_b[0];
            #pragma unroll
            for (int t = 0; t < TW; ++t)
                #pragma unroll
                for (int c = 0; c < NC; ++c)
                    out[((size_t)b * NT + t0 + t) * NC + c] = acc[t][c] + gb;
        }
    }
}

extern "C" void kernel_launch(void* const* d_in, const int* in_sizes, int n_in,
                              void* d_out, int out_size, void* d_ws, size_t ws_size,
                              hipStream_t stream) {
    const float* x_grid   = (const float*)d_in[0];
    const float* h_grid   = (const float*)d_in[1];
    const float* target_x = (const float*)d_in[2];
    const float* sigma    = (const float*)d_in[3];
    const float* g_w      = (const float*)d_in[4];
    const float* g_b      = (const float*)d_in[5];
    float* out = (float*)d_out;

    const int grid = NB * (NT / TT);  // 256 blocks (1 per CU)
    fused_kernel<<<grid, 256, 0, stream>>>(x_grid, h_grid, target_x,
                                           sigma, g_w, g_b, out);
}

// Round 5
// 9.909 us; speedup vs baseline: 2.4309x; 1.0603x over previous
//
#include <hip/hip_runtime.h>

// Problem constants (from reference setup_inputs)
#define NB 8
#define NG 512
#define NT 1024
#define NK 5
#define NC 3
#define TT 16  // targets per block  (grid = 512 -> 2 blocks/CU = 2 waves/SIMD)
#define TW 4   // targets per wave (TT / 4 waves)

// 0.5 * log2(e)
#define HALF_LOG2E 0.72134752044448170f

#if defined(__has_builtin)
#if __has_builtin(__builtin_amdgcn_exp2f)
#define EXP2F(x) __builtin_amdgcn_exp2f(x)
#else
#define EXP2F(x) exp2f(x)
#endif
#else
#define EXP2F(x) exp2f(x)
#endif

// Wave64 sum via DPP (VALU pipe, not LDS pipe). Result valid in lane 63.
template <int CTRL>
__device__ __forceinline__ float dpp_add(float v) {
    int x = __builtin_amdgcn_update_dpp(0, __float_as_int(v), CTRL, 0xf, 0xf, true);
    return v + __int_as_float(x);
}
__device__ __forceinline__ float wave_sum_lane63(float v) {
    v = dpp_add<0x111>(v);  // row_shr:1
    v = dpp_add<0x112>(v);  // row_shr:2
    v = dpp_add<0x114>(v);  // row_shr:4
    v = dpp_add<0x118>(v);  // row_shr:8  -> lane 15 of each 16-row = row sum
    v = dpp_add<0x142>(v);  // row_bcast:15
    v = dpp_add<0x143>(v);  // row_bcast:31 -> lane 63 = wave sum
    return v;
}

__global__ __launch_bounds__(256)
void fused_kernel(const float* __restrict__ x_grid,
                  const float* __restrict__ h_grid,
                  const float* __restrict__ target_x,
                  const float* __restrict__ sigma,
                  const float* __restrict__ g_w,
                  const float* __restrict__ g_b,
                  float* __restrict__ out) {
    // float4-padded SoA tiles: .x/.y/.z = channels, .w = pad. 16 KB total.
    __shared__ float4 xb_s[NG];   // x * beta
    __shared__ float4 hs_s[NG];   // sum_k gw[k] * h

    const int tid   = threadIdx.x;
    const int b     = blockIdx.x / (NT / TT);
    const int ttile = blockIdx.x % (NT / TT);
    const int wave  = tid >> 6;
    const int lane  = tid & 63;
    const int t0    = ttile * TT + wave * TW;

    // Runtime check: sigma identical across k for each c? (uniform branch;
    // true for this module's init -> 5x fewer exps). Fallback stays correct.
    float sig0[NC];
    #pragma unroll
    for (int c = 0; c < NC; ++c) sig0[c] = sigma[c];
    bool kuni = true;
    #pragma unroll
    for (int k = 1; k < NK; ++k)
        #pragma unroll
        for (int c = 0; c < NC; ++c)
            kuni = kuni && (sigma[k * NC + c] == sig0[c]);

    if (kuni) {
        // ---- fast path ----
        float beta[NC];
        #pragma unroll
        for (int c = 0; c < NC; ++c) {
            float s = __expf(sig0[c]) + 1e-6f;
            beta[c] = sqrtf(HALF_LOG2E) / s;
        }
        float gw[NK];
        #pragma unroll
        for (int k = 0; k < NK; ++k) gw[k] = g_w[k];

        // Stage: thread tid owns g = 2*tid, 2*tid+1 -> 30 contiguous h floats
        {
            const float* __restrict__ hp = h_grid + (size_t)b * NG * NK * NC + tid * 2 * NK * NC;
            const float* __restrict__ xp = x_grid + (size_t)b * NG * NC + tid * 2 * NC;
            #pragma unroll
            for (int gg = 0; gg < 2; ++gg) {
                const int g = tid * 2 + gg;
                float hs[NC] = {};
                #pragma unroll
                for (int k = 0; k < NK; ++k)
                    #pragma unroll
                    for (int c = 0; c < NC; ++c)
                        hs[c] += gw[k] * hp[gg * NK * NC + k * NC + c];
                hs_s[g] = make_float4(hs[0], hs[1], hs[2], 0.f);
                xb_s[g] = make_float4(xp[gg * NC + 0] * beta[0],
                                      xp[gg * NC + 1] * beta[1],
                                      xp[gg * NC + 2] * beta[2], 0.f);
            }
        }

        // Target coords (pre-scaled), per wave
        float tb[TW][NC];
        #pragma unroll
        for (int t = 0; t < TW; ++t)
            #pragma unroll
            for (int c = 0; c < NC; ++c)
                tb[t][c] = target_x[((size_t)b * NT + t0 + t) * NC + c] * beta[c];

        __syncthreads();

        float acc[TW][NC] = {};

        // Main loop: lane covers g = lane + 64*i; 2x ds_read_b128 per iter
        #pragma unroll
        for (int i = 0; i < NG / 64; ++i) {
            const int g = lane + i * 64;
            const float4 xv = xb_s[g];
            const float4 hv = hs_s[g];
            #pragma unroll
            for (int t = 0; t < TW; ++t) {
                float a0 = xv.x - tb[t][0];
                float a1 = xv.y - tb[t][1];
                float a2 = xv.z - tb[t][2];
                acc[t][0] += hv.x * EXP2F(-(a0 * a0));
                acc[t][1] += hv.y * EXP2F(-(a1 * a1));
                acc[t][2] += hv.z * EXP2F(-(a2 * a2));
            }
        }

        // DPP wave reduction (VALU pipe); sums land in lane 63
        #pragma unroll
        for (int t = 0; t < TW; ++t)
            #pragma unroll
            for (int c = 0; c < NC; ++c)
                acc[t][c] = wave_sum_lane63(acc[t][c]);

        if (lane == 63) {
            const float gb = g_b[0];
            #pragma unroll
            for (int t = 0; t < TW; ++t)
                #pragma unroll
                for (int c = 0; c < NC; ++c)
                    out[((size_t)b * NT + t0 + t) * NC + c] = acc[t][c] + gb;
        }
    } else {
        // ---- general fallback (arbitrary sigma; reads global directly) ----
        float gw[NK], coef[NK][NC], txr[TW][NC];
        #pragma unroll
        for (int k = 0; k < NK; ++k) gw[k] = g_w[k];
        #pragma unroll
        for (int k = 0; k < NK; ++k)
            #pragma unroll
            for (int c = 0; c < NC; ++c) {
                float s = __expf(sigma[k * NC + c]) + 1e-6f;
                coef[k][c] = -HALF_LOG2E / (s * s);
            }
        #pragma unroll
        for (int t = 0; t < TW; ++t)
            #pragma unroll
            for (int c = 0; c < NC; ++c)
                txr[t][c] = target_x[((size_t)b * NT + t0 + t) * NC + c];

        float acc[TW][NC] = {};

        #pragma unroll 1
        for (int i = 0; i < NG / 64; ++i) {
            const int g = lane + i * 64;
            float xv[NC];
            #pragma unroll
            for (int c = 0; c < NC; ++c)
                xv[c] = x_grid[((size_t)b * NG + g) * NC + c];
            float hv[NK][NC];
            #pragma unroll
            for (int k = 0; k < NK; ++k)
                #pragma unroll
                for (int c = 0; c < NC; ++c)
                    hv[k][c] = gw[k] * h_grid[(((size_t)b * NG + g) * NK + k) * NC + c];
            #pragma unroll
            for (int t = 0; t < TW; ++t) {
                float d2[NC];
                #pragma unroll
                for (int c = 0; c < NC; ++c) {
                    float d = xv[c] - txr[t][c];
                    d2[c] = d * d;
                }
                #pragma unroll
                for (int k = 0; k < NK; ++k)
                    #pragma unroll
                    for (int c = 0; c < NC; ++c)
                        acc[t][c] += hv[k][c] * EXP2F(d2[c] * coef[k][c]);
            }
        }

        #pragma unroll
        for (int t = 0; t < TW; ++t)
            #pragma unroll
            for (int c = 0; c < NC; ++c)
                acc[t][c] = wave_sum_lane63(acc[t][c]);

        if (lane == 63) {
            const float gb = g_b[0];
            #pragma unroll
            for (int t = 0; t < TW; ++t)
                #pragma unroll
                for (int c = 0; c < NC; ++c)
                    out[((size_t)b * NT + t0 + t) * NC + c] = acc[t][c] + gb;
        }
    }
}

extern "C" void kernel_launch(void* const* d_in, const int* in_sizes, int n_in,
                              void* d_out, int out_size, void* d_ws, size_t ws_size,
                              hipStream_t stream) {
    const float* x_grid   = (const float*)d_in[0];
    const float* h_grid   = (const float*)d_in[1];
    const float* target_x = (const float*)d_in[2];
    const float* sigma    = (const float*)d_in[3];
    const float* g_w      = (const float*)d_in[4];
    const float* g_b      = (const float*)d_in[5];
    float* out = (float*)d_out;

    const int grid = NB * (NT / TT);  // 512 blocks (2 per CU)
    fused_kernel<<<grid, 256, 0, stream>>>(x_grid, h_grid, target_x,
                                           sigma, g_w, g_b, out);
}

// Round 6
// 9.653 us; speedup vs baseline: 2.4952x; 1.0264x over previous
//
#include <hip/hip_runtime.h>

// Problem constants (from reference setup_inputs)
#define NB 8
#define NG 512
#define NT 1024
#define NK 5
#define NC 3
#define TT 32  // targets per block
#define NW 8   // waves per block (512 threads)
#define TW 4   // targets per wave (TT / NW)

// 0.5 * log2(e)
#define HALF_LOG2E 0.72134752044448170f

#if defined(__has_builtin)
#if __has_builtin(__builtin_amdgcn_exp2f)
#define EXP2F(x) __builtin_amdgcn_exp2f(x)
#else
#define EXP2F(x) exp2f(x)
#endif
#else
#define EXP2F(x) exp2f(x)
#endif

// Wave64 sum via DPP (VALU pipe, not LDS pipe). Result valid in lane 63.
template <int CTRL>
__device__ __forceinline__ float dpp_add(float v) {
    int x = __builtin_amdgcn_update_dpp(0, __float_as_int(v), CTRL, 0xf, 0xf, true);
    return v + __int_as_float(x);
}
__device__ __forceinline__ float wave_sum_lane63(float v) {
    v = dpp_add<0x111>(v);  // row_shr:1
    v = dpp_add<0x112>(v);  // row_shr:2
    v = dpp_add<0x114>(v);  // row_shr:4
    v = dpp_add<0x118>(v);  // row_shr:8  -> lane 15/31/47/63 = row sums
    v = dpp_add<0x142>(v);  // row_bcast:15
    v = dpp_add<0x143>(v);  // row_bcast:31 -> lane 63 = wave sum
    return v;
}

__global__ __launch_bounds__(512)
void fused_kernel(const float* __restrict__ x_grid,
                  const float* __restrict__ h_grid,
                  const float* __restrict__ target_x,
                  const float* __restrict__ sigma,
                  const float* __restrict__ g_w,
                  const float* __restrict__ g_b,
                  float* __restrict__ out) {
    // float4-padded SoA tiles: .x/.y/.z = channels, .w = pad. 16 KB total.
    __shared__ float4 xb_s[NG];   // x * beta
    __shared__ float4 hs_s[NG];   // sum_k gw[k] * h

    const int tid   = threadIdx.x;
    const int b     = blockIdx.x / (NT / TT);
    const int ttile = blockIdx.x % (NT / TT);
    const int wave  = tid >> 6;
    const int lane  = tid & 63;
    const int t0    = ttile * TT + wave * TW;

    // Runtime check: sigma identical across k for each c? (uniform branch;
    // true for this module's init -> 5x fewer exps). Fallback stays correct.
    float sig0[NC];
    #pragma unroll
    for (int c = 0; c < NC; ++c) sig0[c] = sigma[c];
    bool kuni = true;
    #pragma unroll
    for (int k = 1; k < NK; ++k)
        #pragma unroll
        for (int c = 0; c < NC; ++c)
            kuni = kuni && (sigma[k * NC + c] == sig0[c]);

    if (kuni) {
        // ---- fast path ----
        float beta[NC];
        #pragma unroll
        for (int c = 0; c < NC; ++c) {
            float s = __expf(sig0[c]) + 1e-6f;
            beta[c] = sqrtf(HALF_LOG2E) / s;
        }
        float gw[NK];
        #pragma unroll
        for (int k = 0; k < NK; ++k) gw[k] = g_w[k];

        // Stage: thread tid owns g = tid -> 15 contiguous h floats + 3 x floats
        {
            const int g = tid;
            const float* __restrict__ hp = h_grid + ((size_t)b * NG + g) * NK * NC;
            const float* __restrict__ xp = x_grid + ((size_t)b * NG + g) * NC;
            float hs[NC] = {};
            #pragma unroll
            for (int k = 0; k < NK; ++k)
                #pragma unroll
                for (int c = 0; c < NC; ++c)
                    hs[c] += gw[k] * hp[k * NC + c];
            hs_s[g] = make_float4(hs[0], hs[1], hs[2], 0.f);
            xb_s[g] = make_float4(xp[0] * beta[0],
                                  xp[1] * beta[1],
                                  xp[2] * beta[2], 0.f);
        }

        // Target coords (pre-scaled), per wave
        float tb[TW][NC];
        #pragma unroll
        for (int t = 0; t < TW; ++t)
            #pragma unroll
            for (int c = 0; c < NC; ++c)
                tb[t][c] = target_x[((size_t)b * NT + t0 + t) * NC + c] * beta[c];

        __syncthreads();

        float acc[TW][NC] = {};

        // Main loop: lane covers g = lane + 64*i; 2x ds_read_b128 per iter
        #pragma unroll
        for (int i = 0; i < NG / 64; ++i) {
            const int g = lane + i * 64;
            const float4 xv = xb_s[g];
            const float4 hv = hs_s[g];
            #pragma unroll
            for (int t = 0; t < TW; ++t) {
                float a0 = xv.x - tb[t][0];
                float a1 = xv.y - tb[t][1];
                float a2 = xv.z - tb[t][2];
                acc[t][0] += hv.x * EXP2F(-(a0 * a0));
                acc[t][1] += hv.y * EXP2F(-(a1 * a1));
                acc[t][2] += hv.z * EXP2F(-(a2 * a2));
            }
        }

        // DPP wave reduction (VALU pipe); sums land in lane 63
        #pragma unroll
        for (int t = 0; t < TW; ++t)
            #pragma unroll
            for (int c = 0; c < NC; ++c)
                acc[t][c] = wave_sum_lane63(acc[t][c]);

        if (lane == 63) {
            const float gb = g_b[0];
            #pragma unroll
            for (int t = 0; t < TW; ++t)
                #pragma unroll
                for (int c = 0; c < NC; ++c)
                    out[((size_t)b * NT + t0 + t) * NC + c] = acc[t][c] + gb;
        }
    } else {
        // ---- general fallback (arbitrary sigma; reads global directly) ----
        float gw[NK], coef[NK][NC], txr[TW][NC];
        #pragma unroll
        for (int k = 0; k < NK; ++k) gw[k] = g_w[k];
        #pragma unroll
        for (int k = 0; k < NK; ++k)
            #pragma unroll
            for (int c = 0; c < NC; ++c) {
                float s = __expf(sigma[k * NC + c]) + 1e-6f;
                coef[k][c] = -HALF_LOG2E / (s * s);
            }
        #pragma unroll
        for (int t = 0; t < TW; ++t)
            #pragma unroll
            for (int c = 0; c < NC; ++c)
                txr[t][c] = target_x[((size_t)b * NT + t0 + t) * NC + c];

        float acc[TW][NC] = {};

        #pragma unroll 1
        for (int i = 0; i < NG / 64; ++i) {
            const int g = lane + i * 64;
            float xv[NC];
            #pragma unroll
            for (int c = 0; c < NC; ++c)
                xv[c] = x_grid[((size_t)b * NG + g) * NC + c];
            float hv[NK][NC];
            #pragma unroll
            for (int k = 0; k < NK; ++k)
                #pragma unroll
                for (int c = 0; c < NC; ++c)
                    hv[k][c] = gw[k] * h_grid[(((size_t)b * NG + g) * NK + k) * NC + c];
            #pragma unroll
            for (int t = 0; t < TW; ++t) {
                float d2[NC];
                #pragma unroll
                for (int c = 0; c < NC; ++c) {
                    float d = xv[c] - txr[t][c];
                    d2[c] = d * d;
                }
                #pragma unroll
                for (int k = 0; k < NK; ++k)
                    #pragma unroll
                    for (int c = 0; c < NC; ++c)
                        acc[t][c] += hv[k][c] * EXP2F(d2[c] * coef[k][c]);
            }
        }

        #pragma unroll
        for (int t = 0; t < TW; ++t)
            #pragma unroll
            for (int c = 0; c < NC; ++c)
                acc[t][c] = wave_sum_lane63(acc[t][c]);

        if (lane == 63) {
            const float gb = g_b[0];
            #pragma unroll
            for (int t = 0; t < TW; ++t)
                #pragma unroll
                for (int c = 0; c < NC; ++c)
                    out[((size_t)b * NT + t0 + t) * NC + c] = acc[t][c] + gb;
        }
    }
}

extern "C" void kernel_launch(void* const* d_in, const int* in_sizes, int n_in,
                              void* d_out, int out_size, void* d_ws, size_t ws_size,
                              hipStream_t stream) {
    const float* x_grid   = (const float*)d_in[0];
    const float* h_grid   = (const float*)d_in[1];
    const float* target_x = (const float*)d_in[2];
    const float* sigma    = (const float*)d_in[3];
    const float* g_w      = (const float*)d_in[4];
    const float* g_b      = (const float*)d_in[5];
    float* out = (float*)d_out;

    const int grid = NB * (NT / TT);  // 256 blocks (1 per CU, 8 waves = 2/SIMD)
    fused_kernel<<<grid, 512, 0, stream>>>(x_grid, h_grid, target_x,
                                           sigma, g_w, g_b, out);
}